// Round 1
// baseline (67.234 us; speedup 1.0000x reference)
//
#include <hip/hip_runtime.h>

// HiPPO-LegS signal reconstruction:
//   out = sum_{i=1..256} coef[i-1] * sqrt(2i+1) * P_i(2*t/curr_t - 1)
// Three-term Legendre recurrence per element, 255 steps, fp32.
// Compute-bound on the fp32 VALU (~4 lane-ops/elem/step -> ~6.8us floor).

#define NCOEF 256

__global__ __launch_bounds__(256) void hippo_kernel(
    const float* __restrict__ t,
    const float* __restrict__ coef,
    const int* __restrict__ curr_t,
    float* __restrict__ out,
    int n4)
{
    // Per-degree weights staged in LDS once per block.
    // w[d] = coef[d] * sqrt(2*(d+1)+1), i.e. weight for degree d+1.
    __shared__ float w[NCOEF];
    const int tid = threadIdx.x;
    w[tid] = coef[tid] * sqrtf(2.0f * (float)tid + 3.0f);
    __syncthreads();

    const int gid = blockIdx.x * 256 + tid;
    if (gid >= n4) return;

    const float s = 2.0f / (float)curr_t[0];

    // 4 elements per thread: one float4 load, 4 independent FMA chains (ILP).
    float4 tv = reinterpret_cast<const float4*>(t)[gid];
    float x[4] = { tv.x * s - 1.0f, tv.y * s - 1.0f,
                   tv.z * s - 1.0f, tv.w * s - 1.0f };

    float pm1[4], p[4], acc[4];
    const float w0 = w[0];
#pragma unroll
    for (int e = 0; e < 4; ++e) {
        pm1[e] = 1.0f;      // P_0
        p[e]   = x[e];      // P_1
        acc[e] = w0 * x[e]; // degree-1 term
    }

    // Fully unrolled: a,b constant-fold to literals (no per-step divide).
#pragma unroll
    for (int d = 1; d < NCOEF; ++d) {
        const float a = (2.0f * (float)d + 1.0f) / ((float)d + 1.0f);
        const float b = (float)d / ((float)d + 1.0f);
        const float wd = w[d];  // same-address LDS broadcast, conflict-free
#pragma unroll
        for (int e = 0; e < 4; ++e) {
            // P_{d+1} = a*x*P_d - b*P_{d-1}
            float pn = a * (x[e] * p[e]) - b * pm1[e];
            pm1[e] = p[e];
            p[e]   = pn;
            acc[e] = fmaf(wd, pn, acc[e]);
        }
    }

    reinterpret_cast<float4*>(out)[gid] =
        make_float4(acc[0], acc[1], acc[2], acc[3]);
}

extern "C" void kernel_launch(void* const* d_in, const int* in_sizes, int n_in,
                              void* d_out, int out_size, void* d_ws, size_t ws_size,
                              hipStream_t stream)
{
    const float* t      = (const float*)d_in[0];
    const float* coef   = (const float*)d_in[1];
    const int*   curr_t = (const int*)d_in[2];
    float*       out    = (float*)d_out;

    int n  = in_sizes[0];   // 524288 = 4 * 131072, divisible by 4
    int n4 = n >> 2;
    int blocks = (n4 + 255) / 256;  // 512 blocks of 256 -> 2 blocks/CU
    hippo_kernel<<<blocks, 256, 0, stream>>>(t, coef, curr_t, out, n4);
}